// Round 1
// baseline (244.419 us; speedup 1.0000x reference)
//
#include <hip/hip_runtime.h>
#include <stdint.h>

#define NB 64
#define NS 512
#define NC 256
#define NH 8
#define ND 32

typedef __attribute__((ext_vector_type(8))) short s8v;
typedef __attribute__((ext_vector_type(8))) unsigned short u8v;
typedef __attribute__((ext_vector_type(4))) float f4v;

static __device__ __forceinline__ uint16_t f2bf(float f) {
    uint32_t u = __builtin_bit_cast(uint32_t, f);
    u += 0x7fffu + ((u >> 16) & 1u);
    return (uint16_t)(u >> 16);
}
static __device__ __forceinline__ float bf2f(uint16_t h) {
    uint32_t u = ((uint32_t)h) << 16;
    return __builtin_bit_cast(float, u);
}

// ---------------- Kernel 1: expand relative-position bias ----------------
// bias[h][s][t] = rel_table[ti - tj + 31][li][lj][h], s = ti*16+li, t = tj*16+lj
__global__ __launch_bounds__(256) void bias_fill(const float* __restrict__ rel,
                                                 uint16_t* __restrict__ bias) {
    int id = blockIdx.x * 256 + threadIdx.x;       // 8*512*512 = 2M total
    int t = id & 511, s = (id >> 9) & 511, h = id >> 18;
    int ti = s >> 4, li = s & 15, tj = t >> 4, lj = t & 15;
    int ridx = ((((ti - tj + 31) << 4) + li) << 4) + lj;
    bias[id] = f2bf(rel[ridx * 8 + h]);
}

// ---------------- Kernel 2: QKV GEMM ----------------
// C[m][n] = sum_k X[m][k]*W[n][k] + b[n]; m in [0,32768), n in [0,768)
// writes q (scaled, [bh][s][d]), k ([bh][s][d]), v transposed ([bh][d][s]) as bf16
__global__ __launch_bounds__(256) void qkv_gemm(const float* __restrict__ X,
                                                const float* __restrict__ W,
                                                const float* __restrict__ Bv,
                                                uint16_t* __restrict__ Qo,
                                                uint16_t* __restrict__ Ko,
                                                uint16_t* __restrict__ Vo) {
    __shared__ uint16_t As[128 * 40];
    __shared__ uint16_t Bs[128 * 40];
    const int tid = threadIdx.x;
    const int bn = blockIdx.x * 128;
    const int bm = blockIdx.y * 128;
    const int lane = tid & 63, wv = tid >> 6;
    const int wm = (wv >> 1) * 64, wn = (wv & 1) * 64;
    const int lq = lane & 15, g = lane >> 4;
    const int srow = tid >> 1;
    const int scol = (tid & 1) * 16;

    f4v acc[4][4] = {};

    for (int ks = 0; ks < 8; ++ks) {
        const int k0 = ks * 32;
        __syncthreads();
        {
            const float* src = X + (size_t)(bm + srow) * 256 + k0 + scol;
            f4v a0 = *(const f4v*)(src);
            f4v a1 = *(const f4v*)(src + 4);
            f4v a2 = *(const f4v*)(src + 8);
            f4v a3 = *(const f4v*)(src + 12);
            u8v p0, p1;
            p0[0]=f2bf(a0[0]); p0[1]=f2bf(a0[1]); p0[2]=f2bf(a0[2]); p0[3]=f2bf(a0[3]);
            p0[4]=f2bf(a1[0]); p0[5]=f2bf(a1[1]); p0[6]=f2bf(a1[2]); p0[7]=f2bf(a1[3]);
            p1[0]=f2bf(a2[0]); p1[1]=f2bf(a2[1]); p1[2]=f2bf(a2[2]); p1[3]=f2bf(a2[3]);
            p1[4]=f2bf(a3[0]); p1[5]=f2bf(a3[1]); p1[6]=f2bf(a3[2]); p1[7]=f2bf(a3[3]);
            *(u8v*)(As + srow * 40 + scol)     = p0;
            *(u8v*)(As + srow * 40 + scol + 8) = p1;

            const float* srcb = W + (size_t)(bn + srow) * 256 + k0 + scol;
            f4v b0 = *(const f4v*)(srcb);
            f4v b1 = *(const f4v*)(srcb + 4);
            f4v b2 = *(const f4v*)(srcb + 8);
            f4v b3 = *(const f4v*)(srcb + 12);
            u8v q0, q1;
            q0[0]=f2bf(b0[0]); q0[1]=f2bf(b0[1]); q0[2]=f2bf(b0[2]); q0[3]=f2bf(b0[3]);
            q0[4]=f2bf(b1[0]); q0[5]=f2bf(b1[1]); q0[6]=f2bf(b1[2]); q0[7]=f2bf(b1[3]);
            q1[0]=f2bf(b2[0]); q1[1]=f2bf(b2[1]); q1[2]=f2bf(b2[2]); q1[3]=f2bf(b2[3]);
            q1[4]=f2bf(b3[0]); q1[5]=f2bf(b3[1]); q1[6]=f2bf(b3[2]); q1[7]=f2bf(b3[3]);
            *(u8v*)(Bs + srow * 40 + scol)     = q0;
            *(u8v*)(Bs + srow * 40 + scol + 8) = q1;
        }
        __syncthreads();
        s8v af[4], bf[4];
        #pragma unroll
        for (int i = 0; i < 4; ++i) {
            af[i] = *(const s8v*)(As + (wm + i * 16 + lq) * 40 + g * 8);
            bf[i] = *(const s8v*)(Bs + (wn + i * 16 + lq) * 40 + g * 8);
        }
        #pragma unroll
        for (int mt = 0; mt < 4; ++mt)
            #pragma unroll
            for (int nt = 0; nt < 4; ++nt)
                acc[mt][nt] = __builtin_amdgcn_mfma_f32_16x16x32_bf16(af[mt], bf[nt], acc[mt][nt], 0, 0, 0);
    }

    const int gsel = bn >> 8;   // 0=q, 1=k, 2=v
    const float scl = (gsel == 0) ? 0.35355339059327373f : 1.0f;
    #pragma unroll
    for (int nt = 0; nt < 4; ++nt) {
        const int ng = bn + wn + nt * 16 + lq;
        const float bv = Bv[ng];
        const int c = ng & 255, hh = c >> 5, dd = c & 31;
        #pragma unroll
        for (int mt = 0; mt < 4; ++mt) {
            #pragma unroll
            for (int r = 0; r < 4; ++r) {
                const int m = bm + wm + mt * 16 + g * 4 + r;
                const int b = m >> 9, s = m & 511;
                const uint16_t val = f2bf((acc[mt][nt][r] + bv) * scl);
                if (gsel == 0)      Qo[((size_t)(b * 8 + hh) * 512 + s) * 32 + dd] = val;
                else if (gsel == 1) Ko[((size_t)(b * 8 + hh) * 512 + s) * 32 + dd] = val;
                else                Vo[((size_t)(b * 8 + hh) * 32 + dd) * 512 + s] = val;
            }
        }
    }
}

// ---------------- Kernel 3: attention ----------------
// block = (qt, b, h); 4 waves, each owns 16 q-rows. Swapped QK^T: mfma(K,Q)
// -> lane holds P[q=lane&15][t = tt*16 + g*4 + r] across 32 tiles.
__global__ __launch_bounds__(256) void attn_kern(const uint16_t* __restrict__ Q,
                                                 const uint16_t* __restrict__ K,
                                                 const uint16_t* __restrict__ V,
                                                 const uint16_t* __restrict__ BIAS,
                                                 uint16_t* __restrict__ AO) {
    __shared__ char Psh[65536];                    // 4 waves x 16KB swizzled P
    const int qt = blockIdx.x, b = blockIdx.y, h = blockIdx.z;
    const int tid = threadIdx.x, lane = tid & 63, wv = tid >> 6;
    const int lq = lane & 15, g = lane >> 4;
    const int bh = b * 8 + h;
    const int qw = qt * 64 + wv * 16;              // window-local q base of wave
    char* pw = Psh + wv * 16384;

    s8v qf = *(const s8v*)(Q + ((size_t)bh * 512 + qw + lq) * 32 + g * 8);

    f4v acc[32] = {};
    const uint16_t* kbase = K + (size_t)bh * 16384 + lq * 32 + g * 8;
    const uint16_t* bbase = BIAS + ((size_t)h * 512 + qw + lq) * 512 + g * 4;

    #pragma unroll
    for (int tt = 0; tt < 32; ++tt) {
        s8v kf = *(const s8v*)(kbase + tt * 512);
        acc[tt] = __builtin_amdgcn_mfma_f32_16x16x32_bf16(kf, qf, acc[tt], 0, 0, 0);
        ushort4 bv = *(const ushort4*)(bbase + tt * 16);
        acc[tt][0] += bf2f(bv.x); acc[tt][1] += bf2f(bv.y);
        acc[tt][2] += bf2f(bv.z); acc[tt][3] += bf2f(bv.w);
    }

    // row softmax: row q = lq lives in lanes {lq, lq+16, lq+32, lq+48}
    float m = -3.0e38f;
    #pragma unroll
    for (int tt = 0; tt < 32; ++tt)
        m = fmaxf(m, fmaxf(fmaxf(acc[tt][0], acc[tt][1]), fmaxf(acc[tt][2], acc[tt][3])));
    m = fmaxf(m, __shfl_xor(m, 16));
    m = fmaxf(m, __shfl_xor(m, 32));

    float sum = 0.f;
    #pragma unroll
    for (int tt = 0; tt < 32; ++tt) {
        #pragma unroll
        for (int r = 0; r < 4; ++r) { acc[tt][r] = __expf(acc[tt][r] - m); sum += acc[tt][r]; }
    }
    sum += __shfl_xor(sum, 16);
    sum += __shfl_xor(sum, 32);

    // write P (bf16, unnormalized) to swizzled LDS: byte = q*1024 + t*2
    #pragma unroll
    for (int tt = 0; tt < 32; ++tt) {
        uint32_t lo = (uint32_t)f2bf(acc[tt][0]) | ((uint32_t)f2bf(acc[tt][1]) << 16);
        uint32_t hi = (uint32_t)f2bf(acc[tt][2]) | ((uint32_t)f2bf(acc[tt][3]) << 16);
        int off = (lq << 10) + (tt << 5) + (g << 3);
        *(uint2*)(pw + (off ^ ((lq & 7) << 4))) = make_uint2(lo, hi);
    }

    // PV: out[16q][32d], A = P rows (from LDS), B = V^T rows (global, contiguous)
    f4v o0 = {}, o1 = {};
    const uint16_t* vbase = V + (size_t)bh * 16384 + lq * 512 + g * 8;
    #pragma unroll
    for (int tc = 0; tc < 16; ++tc) {
        int off = (lq << 10) + (tc << 6) + (g << 4);
        s8v pf = *(const s8v*)(pw + (off ^ ((lq & 7) << 4)));
        s8v v0 = *(const s8v*)(vbase + tc * 32);
        s8v v1 = *(const s8v*)(vbase + 8192 + tc * 32);
        o0 = __builtin_amdgcn_mfma_f32_16x16x32_bf16(pf, v0, o0, 0, 0, 0);
        o1 = __builtin_amdgcn_mfma_f32_16x16x32_bf16(pf, v1, o1, 0, 0, 0);
    }

    const float inv = 1.0f / sum;                  // valid for row lq
    #pragma unroll
    for (int r = 0; r < 4; ++r) {
        const float iv = __shfl(inv, g * 4 + r);   // row g*4+r's denom
        const int srow = b * 512 + qt * 64 + wv * 16 + g * 4 + r;
        uint16_t* dst = AO + (size_t)srow * 256 + h * 32 + lq;
        dst[0]  = f2bf(o0[r] * iv);
        dst[16] = f2bf(o1[r] * iv);
    }
}

// ---------------- Kernel 4: output projection ----------------
__global__ __launch_bounds__(256) void proj_gemm(const uint16_t* __restrict__ A,
                                                 const float* __restrict__ W,
                                                 const float* __restrict__ Bv,
                                                 float* __restrict__ Out) {
    __shared__ uint16_t As[128 * 40];
    __shared__ uint16_t Bs[128 * 40];
    const int tid = threadIdx.x;
    const int bn = blockIdx.x * 128;
    const int bm = blockIdx.y * 128;
    const int lane = tid & 63, wv = tid >> 6;
    const int wm = (wv >> 1) * 64, wn = (wv & 1) * 64;
    const int lq = lane & 15, g = lane >> 4;
    const int srow = tid >> 1;
    const int scol = (tid & 1) * 16;

    f4v acc[4][4] = {};

    for (int ks = 0; ks < 8; ++ks) {
        const int k0 = ks * 32;
        __syncthreads();
        {
            const uint16_t* src = A + (size_t)(bm + srow) * 256 + k0 + scol;
            u8v p0 = *(const u8v*)(src);
            u8v p1 = *(const u8v*)(src + 8);
            *(u8v*)(As + srow * 40 + scol)     = p0;
            *(u8v*)(As + srow * 40 + scol + 8) = p1;

            const float* srcb = W + (size_t)(bn + srow) * 256 + k0 + scol;
            f4v b0 = *(const f4v*)(srcb);
            f4v b1 = *(const f4v*)(srcb + 4);
            f4v b2 = *(const f4v*)(srcb + 8);
            f4v b3 = *(const f4v*)(srcb + 12);
            u8v q0, q1;
            q0[0]=f2bf(b0[0]); q0[1]=f2bf(b0[1]); q0[2]=f2bf(b0[2]); q0[3]=f2bf(b0[3]);
            q0[4]=f2bf(b1[0]); q0[5]=f2bf(b1[1]); q0[6]=f2bf(b1[2]); q0[7]=f2bf(b1[3]);
            q1[0]=f2bf(b2[0]); q1[1]=f2bf(b2[1]); q1[2]=f2bf(b2[2]); q1[3]=f2bf(b2[3]);
            q1[4]=f2bf(b3[0]); q1[5]=f2bf(b3[1]); q1[6]=f2bf(b3[2]); q1[7]=f2bf(b3[3]);
            *(u8v*)(Bs + srow * 40 + scol)     = q0;
            *(u8v*)(Bs + srow * 40 + scol + 8) = q1;
        }
        __syncthreads();
        s8v af[4], bf[4];
        #pragma unroll
        for (int i = 0; i < 4; ++i) {
            af[i] = *(const s8v*)(As + (wm + i * 16 + lq) * 40 + g * 8);
            bf[i] = *(const s8v*)(Bs + (wn + i * 16 + lq) * 40 + g * 8);
        }
        #pragma unroll
        for (int mt = 0; mt < 4; ++mt)
            #pragma unroll
            for (int nt = 0; nt < 4; ++nt)
                acc[mt][nt] = __builtin_amdgcn_mfma_f32_16x16x32_bf16(af[mt], bf[nt], acc[mt][nt], 0, 0, 0);
    }

    #pragma unroll
    for (int nt = 0; nt < 4; ++nt) {
        const int n = bn + wn + nt * 16 + lq;
        const float bv = Bv[n];
        #pragma unroll
        for (int mt = 0; mt < 4; ++mt) {
            #pragma unroll
            for (int r = 0; r < 4; ++r) {
                const int mm = bm + wm + mt * 16 + g * 4 + r;
                Out[(size_t)mm * 256 + n] = acc[mt][nt][r] + bv;
            }
        }
    }
}

extern "C" void kernel_launch(void* const* d_in, const int* in_sizes, int n_in,
                              void* d_out, int out_size, void* d_ws, size_t ws_size,
                              hipStream_t stream) {
    const float* x      = (const float*)d_in[0];
    const float* qkv_w  = (const float*)d_in[1];
    const float* qkv_b  = (const float*)d_in[2];
    const float* proj_w = (const float*)d_in[3];
    const float* proj_b = (const float*)d_in[4];
    const float* rel    = (const float*)d_in[5];
    float* out = (float*)d_out;

    uint16_t* ws = (uint16_t*)d_ws;
    const size_t QKV_ELEMS = (size_t)NB * NH * NS * ND;   // 8M each
    uint16_t* Qb   = ws;
    uint16_t* Kb   = Qb + QKV_ELEMS;
    uint16_t* Vb   = Kb + QKV_ELEMS;
    uint16_t* AOb  = Vb + QKV_ELEMS;
    uint16_t* BIAS = AOb + QKV_ELEMS;                     // 2M elems

    bias_fill<<<8192, 256, 0, stream>>>(rel, BIAS);
    qkv_gemm<<<dim3(6, 256), 256, 0, stream>>>(x, qkv_w, qkv_b, Qb, Kb, Vb);
    attn_kern<<<dim3(8, 64, 8), 256, 0, stream>>>(Qb, Kb, Vb, BIAS, AOb);
    proj_gemm<<<dim3(2, 256), 256, 0, stream>>>(AOb, proj_w, proj_b, out);
}

// Round 2
// 234.882 us; speedup vs baseline: 1.0406x; 1.0406x over previous
//
#include <hip/hip_runtime.h>
#include <stdint.h>

#define NB 64
#define NS 512
#define NC 256
#define NH 8
#define ND 32

typedef __attribute__((ext_vector_type(8))) short s8v;
typedef __attribute__((ext_vector_type(8))) unsigned short u8v;
typedef __attribute__((ext_vector_type(4))) float f4v;

#define LOG2E 1.4426950408889634f

static __device__ __forceinline__ uint16_t f2bf(float f) {
    uint32_t u = __builtin_bit_cast(uint32_t, f);
    u += 0x7fffu + ((u >> 16) & 1u);
    return (uint16_t)(u >> 16);
}
static __device__ __forceinline__ float bf2f(uint16_t h) {
    uint32_t u = ((uint32_t)h) << 16;
    return __builtin_bit_cast(float, u);
}
static __device__ __forceinline__ uint32_t cvtpk(float lo, float hi) {
    uint32_t r;
    asm("v_cvt_pk_bf16_f32 %0, %1, %2" : "=v"(r) : "v"(lo), "v"(hi));
    return r;
}

// ---------------- Kernel 0: bulk fp32 -> bf16 convert (n multiple of 2048) ----
__global__ __launch_bounds__(256) void cvt_f2bf(const float* __restrict__ in,
                                                uint16_t* __restrict__ out) {
    int i = (blockIdx.x * 256 + threadIdx.x) * 8;
    f4v a = *(const f4v*)(in + i);
    f4v b = *(const f4v*)(in + i + 4);
    uint4 w;
    w.x = cvtpk(a[0], a[1]); w.y = cvtpk(a[2], a[3]);
    w.z = cvtpk(b[0], b[1]); w.w = cvtpk(b[2], b[3]);
    *(uint4*)(out + i) = w;
}

// ---------------- Kernel 1: expand relative-position bias (pre-scaled by log2e)
__global__ __launch_bounds__(256) void bias_fill(const float* __restrict__ rel,
                                                 uint16_t* __restrict__ bias) {
    int id = blockIdx.x * 256 + threadIdx.x;       // 8*512*512 = 2M total
    int t = id & 511, s = (id >> 9) & 511, h = id >> 18;
    int ti = s >> 4, li = s & 15, tj = t >> 4, lj = t & 15;
    int ridx = ((((ti - tj + 31) << 4) + li) << 4) + lj;
    bias[id] = f2bf(rel[ridx * 8 + h] * LOG2E);
}

// ---------------- Kernel 2: QKV GEMM (A = bf16 X, B = fp32 W) ----------------
// writes q (scaled by SCALE*log2e, [bh][s][d]), k ([bh][s][d]), v^T ([bh][d][s])
__global__ __launch_bounds__(256) void qkv_gemm(const uint16_t* __restrict__ X,
                                                const float* __restrict__ W,
                                                const float* __restrict__ Bv,
                                                uint16_t* __restrict__ Qo,
                                                uint16_t* __restrict__ Ko,
                                                uint16_t* __restrict__ Vo) {
    __shared__ uint16_t As[128 * 40];
    __shared__ uint16_t Bs[128 * 40];
    const int tid = threadIdx.x;
    const int bn = blockIdx.x * 128;
    const int bm = blockIdx.y * 128;
    const int lane = tid & 63, wv = tid >> 6;
    const int wm = (wv >> 1) * 64, wn = (wv & 1) * 64;
    const int lq = lane & 15, g = lane >> 4;
    const int srow = tid >> 1;
    const int scol = (tid & 1) * 16;

    f4v acc[4][4] = {};

    for (int ks = 0; ks < 8; ++ks) {
        const int k0 = ks * 32;
        __syncthreads();
        {
            const uint16_t* src = X + (size_t)(bm + srow) * 256 + k0 + scol;
            u8v p0 = *(const u8v*)(src);
            u8v p1 = *(const u8v*)(src + 8);
            *(u8v*)(As + srow * 40 + scol)     = p0;
            *(u8v*)(As + srow * 40 + scol + 8) = p1;

            const float* srcb = W + (size_t)(bn + srow) * 256 + k0 + scol;
            f4v b0 = *(const f4v*)(srcb);
            f4v b1 = *(const f4v*)(srcb + 4);
            f4v b2 = *(const f4v*)(srcb + 8);
            f4v b3 = *(const f4v*)(srcb + 12);
            uint4 q0, q1;
            q0.x = cvtpk(b0[0], b0[1]); q0.y = cvtpk(b0[2], b0[3]);
            q0.z = cvtpk(b1[0], b1[1]); q0.w = cvtpk(b1[2], b1[3]);
            q1.x = cvtpk(b2[0], b2[1]); q1.y = cvtpk(b2[2], b2[3]);
            q1.z = cvtpk(b3[0], b3[1]); q1.w = cvtpk(b3[2], b3[3]);
            *(uint4*)(Bs + srow * 40 + scol)     = q0;
            *(uint4*)(Bs + srow * 40 + scol + 8) = q1;
        }
        __syncthreads();
        s8v af[4], bf[4];
        #pragma unroll
        for (int i = 0; i < 4; ++i) {
            af[i] = *(const s8v*)(As + (wm + i * 16 + lq) * 40 + g * 8);
            bf[i] = *(const s8v*)(Bs + (wn + i * 16 + lq) * 40 + g * 8);
        }
        #pragma unroll
        for (int mt = 0; mt < 4; ++mt)
            #pragma unroll
            for (int nt = 0; nt < 4; ++nt)
                acc[mt][nt] = __builtin_amdgcn_mfma_f32_16x16x32_bf16(af[mt], bf[nt], acc[mt][nt], 0, 0, 0);
    }

    const int gsel = bn >> 8;   // 0=q, 1=k, 2=v
    const float scl = (gsel == 0) ? (0.35355339059327373f * LOG2E) : 1.0f;
    #pragma unroll
    for (int nt = 0; nt < 4; ++nt) {
        const int ng = bn + wn + nt * 16 + lq;
        const float bv = Bv[ng];
        const int c = ng & 255, hh = c >> 5, dd = c & 31;
        #pragma unroll
        for (int mt = 0; mt < 4; ++mt) {
            #pragma unroll
            for (int r = 0; r < 4; ++r) {
                const int m = bm + wm + mt * 16 + g * 4 + r;
                const int b = m >> 9, s = m & 511;
                const uint16_t val = f2bf((acc[mt][nt][r] + bv) * scl);
                if (gsel == 0)      Qo[((size_t)(b * 8 + hh) * 512 + s) * 32 + dd] = val;
                else if (gsel == 1) Ko[((size_t)(b * 8 + hh) * 512 + s) * 32 + dd] = val;
                else                Vo[((size_t)(b * 8 + hh) * 32 + dd) * 512 + s] = val;
            }
        }
    }
}

// ---------------- Kernel 3: flash attention, online softmax, no LDS ----------
// block = (qt, b, h); 4 waves x 16 q-rows. Swapped QK^T: lane holds
// P[q=lane&15][t = tt*16 + g*4 + r] (log2 domain). KV tiles of 64.
__global__ __launch_bounds__(256) void attn_kern(const uint16_t* __restrict__ Q,
                                                 const uint16_t* __restrict__ K,
                                                 const uint16_t* __restrict__ V,
                                                 const uint16_t* __restrict__ BIAS,
                                                 uint16_t* __restrict__ AO) {
    const int qt = blockIdx.x, b = blockIdx.y, h = blockIdx.z;
    const int tid = threadIdx.x, lane = tid & 63, wv = tid >> 6;
    const int lq = lane & 15, g = lane >> 4;
    const bool godd = (g & 1);
    const bool ghi = (g >= 2);
    const int bh = b * 8 + h;
    const int qw = qt * 64 + wv * 16;              // window-local q base of wave

    s8v qf = *(const s8v*)(Q + ((size_t)bh * 512 + qw + lq) * 32 + g * 8);
    const uint16_t* kbase = K + (size_t)bh * 16384 + lq * 32 + g * 8;
    const uint16_t* vbase = V + (size_t)bh * 16384 + lq * 512 + g * 8;
    const uint16_t* bbase = BIAS + ((size_t)h * 512 + qw + lq) * 512 + g * 4;

    f4v o0 = {}, o1 = {};
    float mrow = -3.0e38f, lrow = 0.f;

    for (int tile = 0; tile < 8; ++tile) {
        const int t0 = tile * 64;
        // ---- S-tile = bias (C-init) + K·Q^T, log2 domain ----
        f4v acc[4];
        #pragma unroll
        for (int tt = 0; tt < 4; ++tt) {
            ushort4 bb = *(const ushort4*)(bbase + t0 + tt * 16);
            acc[tt][0] = bf2f(bb.x); acc[tt][1] = bf2f(bb.y);
            acc[tt][2] = bf2f(bb.z); acc[tt][3] = bf2f(bb.w);
        }
        #pragma unroll
        for (int tt = 0; tt < 4; ++tt) {
            s8v kf = *(const s8v*)(kbase + (t0 + tt * 16) * 32);
            acc[tt] = __builtin_amdgcn_mfma_f32_16x16x32_bf16(kf, qf, acc[tt], 0, 0, 0);
        }
        // ---- row max (row q = lq lives in lanes {lq, lq+16, lq+32, lq+48}) ----
        float pmax = fmaxf(fmaxf(acc[0][0], acc[0][1]), fmaxf(acc[0][2], acc[0][3]));
        #pragma unroll
        for (int tt = 1; tt < 4; ++tt)
            pmax = fmaxf(pmax, fmaxf(fmaxf(acc[tt][0], acc[tt][1]), fmaxf(acc[tt][2], acc[tt][3])));
        pmax = fmaxf(pmax, __shfl_xor(pmax, 16));
        pmax = fmaxf(pmax, __shfl_xor(pmax, 32));

        // ---- online-softmax update, defer-rescale threshold 8 (log2 domain) ----
        if (!__all(pmax - mrow <= 8.0f)) {
            float mnew = fmaxf(mrow, pmax);
            float scale = __builtin_amdgcn_exp2f(mrow - mnew);
            lrow *= scale;
            float s0 = __shfl(scale, g * 4 + 0);
            float s1 = __shfl(scale, g * 4 + 1);
            float s2 = __shfl(scale, g * 4 + 2);
            float s3 = __shfl(scale, g * 4 + 3);
            o0[0] *= s0; o0[1] *= s1; o0[2] *= s2; o0[3] *= s3;
            o1[0] *= s0; o1[1] *= s1; o1[2] *= s2; o1[3] *= s3;
            mrow = mnew;
        }
        // ---- P = exp2(S - m), per-lane partial row-sum ----
        float lsum = 0.f;
        #pragma unroll
        for (int tt = 0; tt < 4; ++tt) {
            #pragma unroll
            for (int r = 0; r < 4; ++r) {
                float p = __builtin_amdgcn_exp2f(acc[tt][r] - mrow);
                acc[tt][r] = p;
                lsum += p;
            }
        }
        lrow += lsum;

        // ---- in-register re-layout P -> PV A-fragments, then PV MFMA ----
        #pragma unroll
        for (int tc = 0; tc < 2; ++tc) {
            uint32_t A0 = cvtpk(acc[2 * tc][0], acc[2 * tc][1]);
            uint32_t A1 = cvtpk(acc[2 * tc][2], acc[2 * tc][3]);
            uint32_t B0 = cvtpk(acc[2 * tc + 1][0], acc[2 * tc + 1][1]);
            uint32_t B1 = cvtpk(acc[2 * tc + 1][2], acc[2 * tc + 1][3]);
            uint32_t xA0 = (uint32_t)__shfl_xor((int)A0, 32);
            uint32_t xA1 = (uint32_t)__shfl_xor((int)A1, 32);
            uint32_t xB0 = (uint32_t)__shfl_xor((int)B0, 32);
            uint32_t xB1 = (uint32_t)__shfl_xor((int)B1, 32);
            uint32_t Ap0 = ghi ? xB0 : A0;   // A' (halves swapped in)
            uint32_t Ap1 = ghi ? xB1 : A1;
            uint32_t Bp0 = ghi ? B0 : xA0;   // B'
            uint32_t Bp1 = ghi ? B1 : xA1;
            uint32_t Z0 = godd ? Ap0 : Bp0;
            uint32_t Z1 = godd ? Ap1 : Bp1;
            uint32_t sZ0 = (uint32_t)__shfl_xor((int)Z0, 16);
            uint32_t sZ1 = (uint32_t)__shfl_xor((int)Z1, 16);
            uint4 wq;
            wq.x = godd ? sZ0 : Ap0;
            wq.y = godd ? sZ1 : Ap1;
            wq.z = godd ? Bp0 : sZ0;
            wq.w = godd ? Bp1 : sZ1;
            s8v pf = __builtin_bit_cast(s8v, wq);
            s8v vf0 = *(const s8v*)(vbase + t0 + tc * 32);
            s8v vf1 = *(const s8v*)(vbase + 8192 + t0 + tc * 32);
            o0 = __builtin_amdgcn_mfma_f32_16x16x32_bf16(pf, vf0, o0, 0, 0, 0);
            o1 = __builtin_amdgcn_mfma_f32_16x16x32_bf16(pf, vf1, o1, 0, 0, 0);
        }
    }

    // ---- finalize: row sum across g, normalize, store ----
    lrow += __shfl_xor(lrow, 16);
    lrow += __shfl_xor(lrow, 32);
    const float inv = 1.0f / lrow;                 // valid for row lq
    #pragma unroll
    for (int r = 0; r < 4; ++r) {
        const float iv = __shfl(inv, g * 4 + r);   // row g*4+r's denom
        const int srow = b * 512 + qw + g * 4 + r;
        uint16_t* dst = AO + (size_t)srow * 256 + h * 32 + lq;
        dst[0]  = f2bf(o0[r] * iv);
        dst[16] = f2bf(o1[r] * iv);
    }
}

// ---------------- Kernel 4: output projection ----------------
__global__ __launch_bounds__(256) void proj_gemm(const uint16_t* __restrict__ A,
                                                 const float* __restrict__ W,
                                                 const float* __restrict__ Bv,
                                                 float* __restrict__ Out) {
    __shared__ uint16_t As[128 * 40];
    __shared__ uint16_t Bs[128 * 40];
    const int tid = threadIdx.x;
    const int bn = blockIdx.x * 128;
    const int bm = blockIdx.y * 128;
    const int lane = tid & 63, wv = tid >> 6;
    const int wm = (wv >> 1) * 64, wn = (wv & 1) * 64;
    const int lq = lane & 15, g = lane >> 4;
    const int srow = tid >> 1;
    const int scol = (tid & 1) * 16;

    f4v acc[4][4] = {};

    for (int ks = 0; ks < 8; ++ks) {
        const int k0 = ks * 32;
        __syncthreads();
        {
            const uint16_t* src = A + (size_t)(bm + srow) * 256 + k0 + scol;
            u8v p0 = *(const u8v*)(src);
            u8v p1 = *(const u8v*)(src + 8);
            *(u8v*)(As + srow * 40 + scol)     = p0;
            *(u8v*)(As + srow * 40 + scol + 8) = p1;

            const float* srcb = W + (size_t)(bn + srow) * 256 + k0 + scol;
            f4v b0 = *(const f4v*)(srcb);
            f4v b1 = *(const f4v*)(srcb + 4);
            f4v b2 = *(const f4v*)(srcb + 8);
            f4v b3 = *(const f4v*)(srcb + 12);
            uint4 q0, q1;
            q0.x = cvtpk(b0[0], b0[1]); q0.y = cvtpk(b0[2], b0[3]);
            q0.z = cvtpk(b1[0], b1[1]); q0.w = cvtpk(b1[2], b1[3]);
            q1.x = cvtpk(b2[0], b2[1]); q1.y = cvtpk(b2[2], b2[3]);
            q1.z = cvtpk(b3[0], b3[1]); q1.w = cvtpk(b3[2], b3[3]);
            *(uint4*)(Bs + srow * 40 + scol)     = q0;
            *(uint4*)(Bs + srow * 40 + scol + 8) = q1;
        }
        __syncthreads();
        s8v af[4], bf[4];
        #pragma unroll
        for (int i = 0; i < 4; ++i) {
            af[i] = *(const s8v*)(As + (wm + i * 16 + lq) * 40 + g * 8);
            bf[i] = *(const s8v*)(Bs + (wn + i * 16 + lq) * 40 + g * 8);
        }
        #pragma unroll
        for (int mt = 0; mt < 4; ++mt)
            #pragma unroll
            for (int nt = 0; nt < 4; ++nt)
                acc[mt][nt] = __builtin_amdgcn_mfma_f32_16x16x32_bf16(af[mt], bf[nt], acc[mt][nt], 0, 0, 0);
    }

    #pragma unroll
    for (int nt = 0; nt < 4; ++nt) {
        const int n = bn + wn + nt * 16 + lq;
        const float bv = Bv[n];
        #pragma unroll
        for (int mt = 0; mt < 4; ++mt) {
            #pragma unroll
            for (int r = 0; r < 4; ++r) {
                const int mm = bm + wm + mt * 16 + g * 4 + r;
                Out[(size_t)mm * 256 + n] = acc[mt][nt][r] + bv;
            }
        }
    }
}

extern "C" void kernel_launch(void* const* d_in, const int* in_sizes, int n_in,
                              void* d_out, int out_size, void* d_ws, size_t ws_size,
                              hipStream_t stream) {
    const float* x      = (const float*)d_in[0];
    const float* qkv_w  = (const float*)d_in[1];
    const float* qkv_b  = (const float*)d_in[2];
    const float* proj_w = (const float*)d_in[3];
    const float* proj_b = (const float*)d_in[4];
    const float* rel    = (const float*)d_in[5];
    float* out = (float*)d_out;

    uint16_t* ws = (uint16_t*)d_ws;
    const size_t QE = (size_t)NB * NH * NS * ND;          // 8,388,608 elems
    uint16_t* Qb   = ws;                                  // 16 MiB
    uint16_t* Kb   = Qb + QE;                             // 16 MiB
    uint16_t* Vb   = Kb + QE;                             // 16 MiB
    uint16_t* Rb   = Vb + QE;                             // 16 MiB: Xbf, then AO
    uint16_t* BIAS = Rb + QE;                             // 4 MiB (2M elems)

    cvt_f2bf<<<4096, 256, 0, stream>>>(x, Rb);            // X -> bf16
    bias_fill<<<8192, 256, 0, stream>>>(rel, BIAS);
    qkv_gemm<<<dim3(6, 256), 256, 0, stream>>>(Rb, qkv_w, qkv_b, Qb, Kb, Vb);
    attn_kern<<<dim3(8, 64, 8), 256, 0, stream>>>(Qb, Kb, Vb, BIAS, Rb);
    proj_gemm<<<dim3(2, 256), 256, 0, stream>>>(Rb, proj_w, proj_b, out);
}